// Round 1
// baseline (631.733 us; speedup 1.0000x reference)
//
#include <hip/hip_runtime.h>
#include <hip/hip_bf16.h>
#include <cstdint>

// Problem constants
#define BB 32
#define SS 2048
#define QQ 1024
#define II 1024
#define AA 1024
#define MM (BB * SS)   // 65536 flattened rows

typedef __bf16 bf16x8 __attribute__((ext_vector_type(8)));
typedef float  f32x4  __attribute__((ext_vector_type(4)));

// Pack two fp32 -> two bf16 (round-half-away via +0x8000, then byte-perm). 3 VALU.
__device__ __forceinline__ unsigned int pack_bf2(float a, float b) {
  unsigned ua = __builtin_bit_cast(unsigned, a) + 0x8000u;
  unsigned ub = __builtin_bit_cast(unsigned, b) + 0x8000u;
  // v_perm_b32: pool bytes 0-3 = s1(ua), 4-7 = s0(ub); take high halves of each.
  return __builtin_amdgcn_perm(ub, ua, 0x07060302u);
}

// ---------------- U transpose+convert: Ut[n][k] = bf16(U[k][n]) ----------------
__global__ void __launch_bounds__(256) k_transpose_u(const float* __restrict__ U,
                                                     unsigned short* __restrict__ Ut) {
  __shared__ float t[64][65];  // +1 pad: conflict-free transpose read
  const int n0 = blockIdx.x * 64, k0 = blockIdx.y * 64;
  const int c = threadIdx.x & 63, r0 = threadIdx.x >> 6;
#pragma unroll
  for (int r = r0; r < 64; r += 4) t[r][c] = U[(size_t)(k0 + r) * AA + n0 + c];
  __syncthreads();
#pragma unroll
  for (int r = r0; r < 64; r += 4) {
    __hip_bfloat16 h = __float2bfloat16(t[c][r]);  // RNE for the reused operand
    Ut[(size_t)(n0 + r) * II + k0 + c] = __builtin_bit_cast(unsigned short, h);
  }
}

// ---------------- pq[b][a] = sum_q queries[b][q] * W[q][a] ----------------
__global__ void __launch_bounds__(128) k_pq(const float* __restrict__ q,
                                            const float* __restrict__ W,
                                            float* __restrict__ pq) {
  const int a  = blockIdx.x * 128 + threadIdx.x;
  const int b  = blockIdx.y;
  const int q0 = blockIdx.z * 256;
  const float* qr = q + b * QQ + q0;        // uniform -> scalar loads
  const float* Wp = W + (size_t)q0 * AA + a;
  float acc = 0.f;
#pragma unroll 8
  for (int i = 0; i < 256; ++i) acc += qr[i] * Wp[(size_t)i * AA];
  atomicAdd(&pq[b * AA + a], acc);
}

// ---------------- fused GEMM: react[m] += sum_n tanh(pq[b][n] + (items@U)[m][n]) * v[n] ----
// Tile 128x128, BK=64, 4 waves (2x2), each wave 4x4 frags of mfma_f32_16x16x32_bf16.
__global__ void __launch_bounds__(256) k_gemm_react(const float* __restrict__ items,
                                                    const unsigned short* __restrict__ Ut,
                                                    const float* __restrict__ pq,
                                                    const float* __restrict__ v,
                                                    float* __restrict__ react) {
  // LDS: bf16 tiles, row = 64 elems = 128 B = 8 chunks of 16 B.
  // Slot (r, c) holds global k-chunk (c ^ (r&7))  -> frag reads land 2-way max.
  __shared__ unsigned short As[128 * 64];
  __shared__ unsigned short Bs[128 * 64];

  const int tid  = threadIdx.x;
  const int lane = tid & 63, wid = tid >> 6;
  const int wm = wid >> 1, wn = wid & 1;
  const int quad = lane >> 4, sx = lane & 15;

  // XCD-aware decode: 8 n-tile siblings of an m-tile get flat ids = mod 8
  // (same XCD under round-robin) and are adjacent in per-XCD order -> A-strip
  // (512 KB) + Ut (2 MB) fit in one 4 MiB L2.
  const unsigned id = blockIdx.x;
  const int xcd = id & 7;
  const int j   = id >> 3;          // 0..511 per-XCD sequence
  const int mtile = xcd + 8 * (j >> 3);
  const int ntile = j & 7;
  const int m0 = mtile * 128, n0 = ntile * 128;
  const int b  = m0 >> 11;          // 2048 rows per batch, 128 | 2048

  // staging maps
  const int ar = tid >> 2;          // A row 0..63 (+64 on 2nd pass)
  const int aq = tid & 3;           // A quarter: floats aq*16..aq*16+15
  const int bn = tid >> 1;          // B row 0..127
  const int bh = tid & 1;           // B chunk-half: chunks bh*4..bh*4+3

  f32x4 acc[4][4] = {};

  for (int kk = 0; kk < 16; ++kk) {
    const int k0 = kk * 64;
    __syncthreads();                // previous iter's frag reads done
    // ---- stage A: fp32 -> bf16, swizzled ----
#pragma unroll
    for (int rr = 0; rr < 2; ++rr) {
      const int r = ar + rr * 64;
      const float* g = items + (size_t)(m0 + r) * II + k0 + aq * 16;
      float4 f0 = ((const float4*)g)[0];
      float4 f1 = ((const float4*)g)[1];
      float4 f2 = ((const float4*)g)[2];
      float4 f3 = ((const float4*)g)[3];
      uint4 w0, w1;
      w0.x = pack_bf2(f0.x, f0.y); w0.y = pack_bf2(f0.z, f0.w);
      w0.z = pack_bf2(f1.x, f1.y); w0.w = pack_bf2(f1.z, f1.w);
      w1.x = pack_bf2(f2.x, f2.y); w1.y = pack_bf2(f2.z, f2.w);
      w1.z = pack_bf2(f3.x, f3.y); w1.w = pack_bf2(f3.z, f3.w);
      const int c0 = (2 * aq) ^ (r & 7);
      const int c1 = (2 * aq + 1) ^ (r & 7);
      *(uint4*)&As[r * 64 + c0 * 8] = w0;
      *(uint4*)&As[r * 64 + c1 * 8] = w1;
    }
    // ---- stage B: already bf16, 16B copies, swizzled ----
    {
      const unsigned short* g = Ut + (size_t)(n0 + bn) * II + k0 + bh * 32;
#pragma unroll
      for (int jj = 0; jj < 4; ++jj) {
        uint4 w = ((const uint4*)g)[jj];
        const int c = (bh * 4 + jj) ^ (bn & 7);
        *(uint4*)&Bs[bn * 64 + c * 8] = w;
      }
    }
    __syncthreads();
    // ---- compute: 2 k-steps x 16 MFMA per wave ----
#pragma unroll
    for (int ks = 0; ks < 2; ++ks) {
      bf16x8 af[4], bfv[4];
#pragma unroll
      for (int mi = 0; mi < 4; ++mi) {
        const int r = wm * 64 + mi * 16 + sx;
        const int c = (ks * 4 + quad) ^ (r & 7);
        af[mi] = *(const bf16x8*)&As[r * 64 + c * 8];
      }
#pragma unroll
      for (int ni = 0; ni < 4; ++ni) {
        const int r = wn * 64 + ni * 16 + sx;
        const int c = (ks * 4 + quad) ^ (r & 7);
        bfv[ni] = *(const bf16x8*)&Bs[r * 64 + c * 8];
      }
#pragma unroll
      for (int mi = 0; mi < 4; ++mi)
#pragma unroll
        for (int ni = 0; ni < 4; ++ni)
          acc[mi][ni] = __builtin_amdgcn_mfma_f32_16x16x32_bf16(af[mi], bfv[ni], acc[mi][ni], 0, 0, 0);
    }
  }

  // ---- epilogue: x=acc+pq; tanh; *v; reduce over this wave's 64 n-cols; atomic ----
  float pqv[4], vv[4];
#pragma unroll
  for (int ni = 0; ni < 4; ++ni) {
    const int n = n0 + wn * 64 + ni * 16 + sx;
    pqv[ni] = pq[b * AA + n];
    vv[ni]  = v[n];
  }
#pragma unroll
  for (int mi = 0; mi < 4; ++mi) {
#pragma unroll
    for (int reg = 0; reg < 4; ++reg) {
      float ssum = 0.f;
#pragma unroll
      for (int ni = 0; ni < 4; ++ni) {
        const float x = acc[mi][ni][reg] + pqv[ni];
        const float e = __expf(2.f * x);
        const float t = 1.f - 2.f * __builtin_amdgcn_rcpf(e + 1.f);  // tanh(x)
        ssum += t * vv[ni];
      }
      // C/D layout: col = lane&15, row = quad*4+reg. Sum the 16 cols.
      ssum += __shfl_xor(ssum, 1);
      ssum += __shfl_xor(ssum, 2);
      ssum += __shfl_xor(ssum, 4);
      ssum += __shfl_xor(ssum, 8);
      if (sx == 0) {
        const int m = m0 + wm * 64 + mi * 16 + quad * 4 + reg;
        atomicAdd(&react[m], ssum);
      }
    }
  }
}

// ---------------- masked softmax over S per batch ----------------
__global__ void __launch_bounds__(256) k_softmax(const float* __restrict__ react,
                                                 const int* __restrict__ weights,
                                                 float* __restrict__ scores) {
  const int b = blockIdx.x, tid = threadIdx.x;
  const int lane = tid & 63, wid = tid >> 6;
  __shared__ float redm[4], reds[4];
  float vals[8];
  float mx = -3.0e38f;
#pragma unroll
  for (int j = 0; j < 8; ++j) {
    const int s = j * 256 + tid;
    const float r = react[b * SS + s];
    const int w = weights[b * SS + s];
    const float val = (w != 0) ? r : -3.0e38f;
    vals[j] = val;
    mx = fmaxf(mx, val);
  }
#pragma unroll
  for (int off = 1; off < 64; off <<= 1) mx = fmaxf(mx, __shfl_xor(mx, off));
  if (lane == 0) redm[wid] = mx;
  __syncthreads();
  mx = fmaxf(fmaxf(redm[0], redm[1]), fmaxf(redm[2], redm[3]));
  float e[8], sum = 0.f;
#pragma unroll
  for (int j = 0; j < 8; ++j) {
    e[j] = (vals[j] < -1.0e38f) ? 0.f : __expf(vals[j] - mx);
    sum += e[j];
  }
#pragma unroll
  for (int off = 1; off < 64; off <<= 1) sum += __shfl_xor(sum, off);
  if (lane == 0) reds[wid] = sum;
  __syncthreads();
  const float inv = 1.f / (reds[0] + reds[1] + reds[2] + reds[3]);
#pragma unroll
  for (int j = 0; j < 8; ++j) scores[b * SS + j * 256 + tid] = e[j] * inv;
}

// ---------------- blended[b][i] = sum_s scores[b][s] * items[b][s][i] ----------------
__global__ void __launch_bounds__(256) k_blended(const float* __restrict__ items,
                                                 const float* __restrict__ scores,
                                                 float* __restrict__ out) {
  const int b = blockIdx.x, s0 = blockIdx.y * 256;
  __shared__ float sc[256];
  sc[threadIdx.x] = scores[b * SS + s0 + threadIdx.x];
  __syncthreads();
  const float4* base = (const float4*)(items + (size_t)b * SS * II + (size_t)s0 * II);
  float4 acc = {0.f, 0.f, 0.f, 0.f};
  for (int s = 0; s < 256; ++s) {
    const float w = sc[s];           // block-uniform: no divergence
    if (w != 0.f) {                  // masked rows are exact zeros -> skip ~half the reads
      const float4 it = base[s * 256 + threadIdx.x];
      acc.x += w * it.x; acc.y += w * it.y; acc.z += w * it.z; acc.w += w * it.w;
    }
  }
  float* o = out + b * II + threadIdx.x * 4;
  atomicAdd(o + 0, acc.x);
  atomicAdd(o + 1, acc.y);
  atomicAdd(o + 2, acc.z);
  atomicAdd(o + 3, acc.w);
}

extern "C" void kernel_launch(void* const* d_in, const int* in_sizes, int n_in,
                              void* d_out, int out_size, void* d_ws, size_t ws_size,
                              hipStream_t stream) {
  const float* queries = (const float*)d_in[0];
  const float* items   = (const float*)d_in[1];
  const int*   weights = (const int*)d_in[2];
  const float* W       = (const float*)d_in[3];
  const float* U       = (const float*)d_in[4];
  const float* v       = (const float*)d_in[5];
  float* out = (float*)d_out;

  char* ws = (char*)d_ws;
  unsigned short* Ut = (unsigned short*)ws;                       // 2 MB  bf16 U^T [n][k]
  float* pq    = (float*)(ws + (2u << 20));                       // 128 KB
  float* react = (float*)(ws + (2u << 20) + (128u << 10));        // 256 KB

  hipMemsetAsync(pq, 0, BB * AA * sizeof(float), stream);
  hipMemsetAsync(react, 0, MM * sizeof(float), stream);
  hipMemsetAsync(out, 0, BB * II * sizeof(float), stream);        // blended region (atomics)

  k_transpose_u<<<dim3(16, 16), 256, 0, stream>>>(U, Ut);
  k_pq<<<dim3(8, BB, 4), 128, 0, stream>>>(queries, W, pq);
  k_gemm_react<<<dim3(4096), 256, 0, stream>>>(items, Ut, pq, v, react);
  k_softmax<<<dim3(BB), 256, 0, stream>>>(react, weights, out + BB * II);
  k_blended<<<dim3(BB, 8), 256, 0, stream>>>(items, out + BB * II, out);
}